// Round 15
// baseline (100.504 us; speedup 1.0000x reference)
//
#include <hip/hip_runtime.h>
#include <hip/hip_bf16.h>

typedef __attribute__((ext_vector_type(8))) short short8;  // 8 bf16 (4 VGPRs)
typedef __attribute__((ext_vector_type(4))) short short4v;
typedef __attribute__((ext_vector_type(4))) float f32x4;
typedef __attribute__((ext_vector_type(2))) float f32x2;

#define INF_BITS 0x7F800000u

// ---------------------------------------------------------------------------
// prep: fp32 -> bf16, h-norms (-0.5*||.||^2, fp32 exact), init min arrays.
// ---------------------------------------------------------------------------
__global__ __launch_bounds__(256) void ahd_prep(
    const float* __restrict__ s1, const float* __restrict__ s2,
    __hip_bfloat16* __restrict__ abf, __hip_bfloat16* __restrict__ bbf,
    float* __restrict__ xh, float* __restrict__ yh,
    unsigned int* __restrict__ rmin, unsigned int* __restrict__ cmin,
    int N, int M)
{
    const int t   = blockIdx.x * 256 + threadIdx.x;
    const int row = t >> 4;
    const int sub = t & 15;

    if (t < N)          rmin[t]     = INF_BITS;
    else if (t < N + M) cmin[t - N] = INF_BITS;

    const float* src; __hip_bfloat16* dst; float* nrm; int r;
    if (row < N)            { src = s1; dst = abf; nrm = xh; r = row; }
    else if (row < N + M)   { src = s2; dst = bbf; nrm = yh; r = row - N; }
    else return;

    const float4 v = *(const float4*)&src[(size_t)r * 64 + sub * 4];
    __hip_bfloat16 h0 = __float2bfloat16(v.x), h1 = __float2bfloat16(v.y);
    __hip_bfloat16 h2 = __float2bfloat16(v.z), h3 = __float2bfloat16(v.w);
    short4v sv = { *(short*)&h0, *(short*)&h1, *(short*)&h2, *(short*)&h3 };
    *(short4v*)&dst[(size_t)r * 64 + sub * 4] = sv;

    float ss = v.x * v.x + v.y * v.y + v.z * v.z + v.w * v.w;
    ss += __shfl_xor(ss, 1);
    ss += __shfl_xor(ss, 2);
    ss += __shfl_xor(ss, 4);
    ss += __shfl_xor(ss, 8);
    if (sub == 0) nrm[r] = -0.5f * ss;     // fold: MFMA C-init = xh + yh
}

// ---------------------------------------------------------------------------
// fused distance-GEMM + row/col min. R14 base (91us) + WAVE PHASE-STAGGER:
// R14 lesson -- absolute VALU-busy fell 61->46us across R12-R14 while wall
// time stayed ~92: the stall is the 4 waves marching in LOCKSTEP through
// identical {ds_read | MFMA | VALU} phases, so the two issue pipes alternate
// instead of overlapping (MfmaUtil 15 + VALUBusy 50 = 65% issue, 35% dead).
// Fix: wave w processes col-tile-pairs in rotated order tile=(k+w)&3 --
// ~300cyc phase offset makes one wave's MFMA burst overlap the others'
// epilogue/ds_reads. Rotation is runtime-uniform: y-norms come from a tiny
// LDS table (ldsY, ds_read per tile), B offsets are base + tile*4096 (exact
// in swizzled space). Everything else identical to R14.
// ---------------------------------------------------------------------------
__global__ __launch_bounds__(256) void ahd_gemm(
    const __hip_bfloat16* __restrict__ abf, const __hip_bfloat16* __restrict__ bbf,
    const float* __restrict__ xh, const float* __restrict__ yh,
    unsigned int* __restrict__ rmin, unsigned int* __restrict__ cmin)
{
    __shared__ __attribute__((aligned(128))) char ldsB[16384];
    __shared__ float rowbuf[4][4][8][17];   // [w][lh][lr<8][j16 +pad] = 8704 B
    __shared__ float colbuf[4][128];
    __shared__ float ldsY[128];

    const int tid  = threadIdx.x;
    const int lane = tid & 63;
    const int w    = tid >> 6;
    const int lr   = lane & 15, lh = lane >> 4;   // lh in 0..3

    const int brow = blockIdx.x * 256;
    const int bcol = blockIdx.y * 128;

    // ---- stage B (16 KB): linear LDS dest + inverse-swizzled source
    const char* bT = (const char*)bbf + (size_t)bcol * 128;
    #pragma unroll
    for (int it = 0; it < 4; ++it) {
        const int dst = w * 1024 + it * 4096;
        const int o   = dst + lane * 16;
        const int so  = o ^ ((o >> 3) & 0x70);
        __builtin_amdgcn_global_load_lds(
            (const __attribute__((address_space(1))) void*)(bT + so),
            (__attribute__((address_space(3))) void*)(ldsB + dst), 16, 0, 0);
    }

    // ---- A fragments straight from global (wave-exclusive 64 rows, L2-hot)
    const char* aB = (const char*)abf + (size_t)(brow + w * 64 + lr) * 128 + lh * 16;
    short8 afr[2][4];   // [ks][m]
    #pragma unroll
    for (int m = 0; m < 4; ++m) {
        afr[0][m] = *(const short8*)(aB + m * 2048);
        afr[1][m] = *(const short8*)(aB + m * 2048 + 64);
    }

    // ---- norms while staging is in flight; y table into LDS
    f32x2 xqlo[4], xqhi[4];
    #pragma unroll
    for (int m = 0; m < 4; ++m) {
        const f32x4 xv = *(const f32x4*)&xh[brow + w * 64 + m * 16 + lh * 4];
        xqlo[m] = (f32x2){xv[0], xv[1]};
        xqhi[m] = (f32x2){xv[2], xv[3]};
    }
    if (tid < 128) ldsY[tid] = yh[bcol + tid];

    __syncthreads();   // drains B staging; ldsY visible

    // ---- hoisted swizzled B-frag base offsets (+4096 per tile-pair is exact
    //      in swizzled space: XOR reads bits 9:7, writes 6:4)
    int ob00 = lr * 128 + lh * 16;              ob00 ^= (ob00 >> 3) & 0x70;
    int ob01 = lr * 128 + 64 + lh * 16;         ob01 ^= (ob01 >> 3) & 0x70;
    int ob10 = (16 + lr) * 128 + lh * 16;       ob10 ^= (ob10 >> 3) & 0x70;
    int ob11 = (16 + lr) * 128 + 64 + lh * 16;  ob11 ^= (ob11 >> 3) & 0x70;

    f32x4 rowm[4];
    #pragma unroll
    for (int m = 0; m < 4; ++m) rowm[m] = (f32x4){-1e30f, -1e30f, -1e30f, -1e30f};

    // ---- 4 tile-pairs in wave-rotated order (phase stagger)
    #pragma unroll
    for (int k = 0; k < 4; ++k) {
        const int tile = (k + w) & 3;          // runtime-uniform per wave
        const int tb   = tile * 4096;          // swizzle-exact tile stride
        const int tc   = tile * 32;

        const float ya = ldsY[tc + lr];
        const float yb = ldsY[tc + 16 + lr];
        const short8 b00 = *(const short8*)(ldsB + ob00 + tb);
        const short8 b01 = *(const short8*)(ldsB + ob01 + tb);
        const short8 b10 = *(const short8*)(ldsB + ob10 + tb);
        const short8 b11 = *(const short8*)(ldsB + ob11 + tb);

        const f32x2 ya2 = {ya, ya}, yb2 = {yb, yb};
        float cm0 = -1e30f, cm1 = -1e30f;
        #pragma unroll
        for (int m = 0; m < 4; ++m) {
            const f32x2 p0 = xqlo[m] + ya2, p1 = xqhi[m] + ya2;  // v_pk_add
            const f32x2 q0 = xqlo[m] + yb2, q1 = xqhi[m] + yb2;
            f32x4 c0 = {p0.x, p0.y, p1.x, p1.y};
            f32x4 c1 = {q0.x, q0.y, q1.x, q1.y};
            c0 = __builtin_amdgcn_mfma_f32_16x16x32_bf16(afr[0][m], b00, c0, 0, 0, 0);
            c1 = __builtin_amdgcn_mfma_f32_16x16x32_bf16(afr[0][m], b10, c1, 0, 0, 0);
            c0 = __builtin_amdgcn_mfma_f32_16x16x32_bf16(afr[1][m], b01, c0, 0, 0, 0);
            c1 = __builtin_amdgcn_mfma_f32_16x16x32_bf16(afr[1][m], b11, c1, 0, 0, 0);
            rowm[m][0] = fmaxf(fmaxf(c0[0], c1[0]), rowm[m][0]);   // v_max3
            rowm[m][1] = fmaxf(fmaxf(c0[1], c1[1]), rowm[m][1]);
            rowm[m][2] = fmaxf(fmaxf(c0[2], c1[2]), rowm[m][2]);
            rowm[m][3] = fmaxf(fmaxf(c0[3], c1[3]), rowm[m][3]);
            cm0 = fmaxf(fmaxf(fmaxf(c0[0], c0[1]), fmaxf(c0[2], c0[3])), cm0);
            cm1 = fmaxf(fmaxf(fmaxf(c1[0], c1[1]), fmaxf(c1[2], c1[3])), cm1);
        }
        cm0 = fmaxf(cm0, __shfl_xor(cm0, 16));
        cm0 = fmaxf(cm0, __shfl_xor(cm0, 32));
        cm1 = fmaxf(cm1, __shfl_xor(cm1, 16));
        cm1 = fmaxf(cm1, __shfl_xor(cm1, 32));
        if (lh == 0) {
            colbuf[w][tc + lr]      = cm0;
            colbuf[w][tc + 16 + lr] = cm1;
        }
    }

    // ---- row partials: xor8 pre-reduce, conflict-free transpose into rowbuf
    #pragma unroll
    for (int m = 0; m < 4; ++m)
        #pragma unroll
        for (int j = 0; j < 4; ++j) {
            float v = rowm[m][j];
            v = fmaxf(v, __shfl_xor(v, 8));
            if (lr < 8) rowbuf[w][lh][lr][m * 4 + j] = v;
        }

    __syncthreads();   // rowbuf + colbuf complete

    // ---- row flush: each thread owns ONE of the block's 256 rows
    {
        const int rw = tid >> 6, rr = tid & 63;
        const int rm = rr >> 4, rlh = (rr >> 2) & 3, rj = rr & 3;
        const float* p = &rowbuf[rw][rlh][0][rm * 4 + rj];
        float v = p[0];
        v = fmaxf(v, p[17]);
        v = fmaxf(v, p[2 * 17]);
        v = fmaxf(v, p[3 * 17]);
        v = fmaxf(v, p[4 * 17]);
        v = fmaxf(v, p[5 * 17]);
        v = fmaxf(v, p[6 * 17]);
        v = fmaxf(v, p[7 * 17]);
        const float d2 = fmaxf(-2.f * v, 0.f);
        atomicMin(&rmin[brow + tid], __float_as_uint(d2));
    }

    // ---- col flush: merge the 4 wave slices, 1 col per thread (tid<128)
    if (tid < 128) {
        const float v = fmaxf(fmaxf(colbuf[0][tid], colbuf[1][tid]),
                              fmaxf(colbuf[2][tid], colbuf[3][tid]));
        const float d2 = fmaxf(-2.f * v, 0.f);
        atomicMin(&cmin[bcol + tid], __float_as_uint(d2));
    }
}

// ---------------------------------------------------------------------------
// finalize: out = mean(sqrt(rmin)) + mean(sqrt(cmin)); 1024 thr, uint4 loads.
// ---------------------------------------------------------------------------
__global__ __launch_bounds__(1024) void ahd_finalize(
    const unsigned int* __restrict__ rmin, const unsigned int* __restrict__ cmin,
    float* __restrict__ out, int N, int M)
{
    const int tid = threadIdx.x;
    const uint4* r4 = (const uint4*)rmin;
    const uint4* c4 = (const uint4*)cmin;
    float sa = 0.f, sb = 0.f;
    for (int i = tid; i < (N >> 2); i += 1024) {
        const uint4 v = r4[i];
        sa += sqrtf(__uint_as_float(v.x)) + sqrtf(__uint_as_float(v.y))
            + sqrtf(__uint_as_float(v.z)) + sqrtf(__uint_as_float(v.w));
    }
    for (int i = tid; i < (M >> 2); i += 1024) {
        const uint4 v = c4[i];
        sb += sqrtf(__uint_as_float(v.x)) + sqrtf(__uint_as_float(v.y))
            + sqrtf(__uint_as_float(v.z)) + sqrtf(__uint_as_float(v.w));
    }
    float v = sa / (float)N + sb / (float)M;
    #pragma unroll
    for (int s = 1; s < 64; s <<= 1) v += __shfl_xor(v, s);
    __shared__ float red[16];
    if ((tid & 63) == 0) red[tid >> 6] = v;
    __syncthreads();
    if (tid == 0) {
        float t = 0.f;
        #pragma unroll
        for (int i = 0; i < 16; ++i) t += red[i];
        out[0] = t;
    }
}

extern "C" void kernel_launch(void* const* d_in, const int* in_sizes, int n_in,
                              void* d_out, int out_size, void* d_ws, size_t ws_size,
                              hipStream_t stream) {
    const float* s1 = (const float*)d_in[0];
    const float* s2 = (const float*)d_in[1];
    const int N = in_sizes[0] / 64;
    const int M = in_sizes[1] / 64;

    char* ws = (char*)d_ws;
    __hip_bfloat16* abf = (__hip_bfloat16*)ws;
    __hip_bfloat16* bbf = (__hip_bfloat16*)(ws + (size_t)N * 128);
    float* xh = (float*)(ws + (size_t)(N + M) * 128);
    float* yh = xh + N;
    unsigned int* rmin = (unsigned int*)(yh + M);
    unsigned int* cmin = rmin + N;

    const int prows = ((N + M) * 16 + 255) / 256;
    ahd_prep<<<prows, 256, 0, stream>>>(s1, s2, abf, bbf, xh, yh,
                                        rmin, cmin, N, M);
    dim3 grid(N / 256, M / 128);    // 8192 blocks; x fastest; NO XCD swizzle
    ahd_gemm<<<grid, 256, 0, stream>>>(abf, bbf, xh, yh, rmin, cmin);
    ahd_finalize<<<1, 1024, 0, stream>>>(rmin, cmin, (float*)d_out, N, M);
}

// Round 16
// 80.739 us; speedup vs baseline: 1.2448x; 1.2448x over previous
//
#include <hip/hip_runtime.h>
#include <hip/hip_bf16.h>

typedef __attribute__((ext_vector_type(8))) short short8;  // 8 bf16 (4 VGPRs)
typedef __attribute__((ext_vector_type(4))) short short4v;
typedef __attribute__((ext_vector_type(4))) float f32x4;
typedef __attribute__((ext_vector_type(2))) float f32x2;

#define INF_BITS 0x7F800000u

// guaranteed single-instruction 3-input max (T17: clang fusion is unreliable)
__device__ __forceinline__ float max3f(float a, float b, float c) {
    float d;
    asm("v_max3_f32 %0, %1, %2, %3" : "=v"(d) : "v"(a), "v"(b), "v"(c));
    return d;
}

// ---------------------------------------------------------------------------
// prep: fp32 -> bf16, h-norms (-0.5*||.||^2, fp32 exact), init min arrays.
// ---------------------------------------------------------------------------
__global__ __launch_bounds__(256) void ahd_prep(
    const float* __restrict__ s1, const float* __restrict__ s2,
    __hip_bfloat16* __restrict__ abf, __hip_bfloat16* __restrict__ bbf,
    float* __restrict__ xh, float* __restrict__ yh,
    unsigned int* __restrict__ rmin, unsigned int* __restrict__ cmin,
    int N, int M)
{
    const int t   = blockIdx.x * 256 + threadIdx.x;
    const int row = t >> 4;
    const int sub = t & 15;

    if (t < N)          rmin[t]     = INF_BITS;
    else if (t < N + M) cmin[t - N] = INF_BITS;

    const float* src; __hip_bfloat16* dst; float* nrm; int r;
    if (row < N)            { src = s1; dst = abf; nrm = xh; r = row; }
    else if (row < N + M)   { src = s2; dst = bbf; nrm = yh; r = row - N; }
    else return;

    const float4 v = *(const float4*)&src[(size_t)r * 64 + sub * 4];
    __hip_bfloat16 h0 = __float2bfloat16(v.x), h1 = __float2bfloat16(v.y);
    __hip_bfloat16 h2 = __float2bfloat16(v.z), h3 = __float2bfloat16(v.w);
    short4v sv = { *(short*)&h0, *(short*)&h1, *(short*)&h2, *(short*)&h3 };
    *(short4v*)&dst[(size_t)r * 64 + sub * 4] = sv;

    float ss = v.x * v.x + v.y * v.y + v.z * v.z + v.w * v.w;
    ss += __shfl_xor(ss, 1);
    ss += __shfl_xor(ss, 2);
    ss += __shfl_xor(ss, 4);
    ss += __shfl_xor(ss, 8);
    if (sub == 0) nrm[r] = -0.5f * ss;     // fold: MFMA C-init = xh + yh
}

// ---------------------------------------------------------------------------
// fused distance-GEMM + row/col min. R14 base (91us, best) with FORCED
// v_max3_f32 emission (R15 lesson: counter arithmetic shows ~1800 emitted
// VALU inst/wave vs ~350 in source -- un-fused fmax pairs are the prime
// suspect; phase-stagger was null and is reverted). Structure unchanged:
// block 256x128, 4 waves x (64 rows x 128 cols), B block-deduped via
// global_load_lds + involution, A/x/y straight from global, C-init fold
// (min d^2 == max acc), LDS-transpose row flush, 2 barriers, no XCD swizzle.
// ---------------------------------------------------------------------------
__global__ __launch_bounds__(256) void ahd_gemm(
    const __hip_bfloat16* __restrict__ abf, const __hip_bfloat16* __restrict__ bbf,
    const float* __restrict__ xh, const float* __restrict__ yh,
    unsigned int* __restrict__ rmin, unsigned int* __restrict__ cmin)
{
    __shared__ __attribute__((aligned(128))) char ldsB[16384];
    __shared__ float rowbuf[4][4][8][17];   // [w][lh][lr<8][j16 +pad] = 8704 B
    __shared__ float colbuf[4][128];

    const int tid  = threadIdx.x;
    const int lane = tid & 63;
    const int w    = tid >> 6;
    const int lr   = lane & 15, lh = lane >> 4;   // lh in 0..3

    const int brow = blockIdx.x * 256;
    const int bcol = blockIdx.y * 128;

    // ---- stage B (16 KB): linear LDS dest + inverse-swizzled source
    const char* bT = (const char*)bbf + (size_t)bcol * 128;
    #pragma unroll
    for (int it = 0; it < 4; ++it) {
        const int dst = w * 1024 + it * 4096;
        const int o   = dst + lane * 16;
        const int so  = o ^ ((o >> 3) & 0x70);
        __builtin_amdgcn_global_load_lds(
            (const __attribute__((address_space(1))) void*)(bT + so),
            (__attribute__((address_space(3))) void*)(ldsB + dst), 16, 0, 0);
    }

    // ---- A fragments straight from global (wave-exclusive 64 rows, L2-hot)
    const char* aB = (const char*)abf + (size_t)(brow + w * 64 + lr) * 128 + lh * 16;
    short8 afr[2][4];   // [ks][m]
    #pragma unroll
    for (int m = 0; m < 4; ++m) {
        afr[0][m] = *(const short8*)(aB + m * 2048);
        afr[1][m] = *(const short8*)(aB + m * 2048 + 64);
    }

    // ---- norms while staging is in flight
    f32x2 xqlo[4], xqhi[4];
    #pragma unroll
    for (int m = 0; m < 4; ++m) {
        const f32x4 xv = *(const f32x4*)&xh[brow + w * 64 + m * 16 + lh * 4];
        xqlo[m] = (f32x2){xv[0], xv[1]};
        xqhi[m] = (f32x2){xv[2], xv[3]};
    }
    const float yv0 = yh[bcol + lr];
    const float yv1 = yh[bcol + 16 + lr];
    const float yv2 = yh[bcol + 32 + lr];
    const float yv3 = yh[bcol + 48 + lr];
    const float yv4 = yh[bcol + 64 + lr];
    const float yv5 = yh[bcol + 80 + lr];
    const float yv6 = yh[bcol + 96 + lr];
    const float yv7 = yh[bcol + 112 + lr];

    __syncthreads();   // drains B staging

    // ---- hoisted swizzled B-frag base offsets (+2048 per n-frag is exact in
    //      swizzled space: XOR reads bits 9:7, writes 6:4)
    int ob00 = lr * 128 + lh * 16;              ob00 ^= (ob00 >> 3) & 0x70;
    int ob01 = lr * 128 + 64 + lh * 16;         ob01 ^= (ob01 >> 3) & 0x70;
    int ob10 = (16 + lr) * 128 + lh * 16;       ob10 ^= (ob10 >> 3) & 0x70;
    int ob11 = (16 + lr) * 128 + 64 + lh * 16;  ob11 ^= (ob11 >> 3) & 0x70;

    f32x4 rowm[4];
    #pragma unroll
    for (int m = 0; m < 4; ++m) rowm[m] = (f32x4){-1e30f, -1e30f, -1e30f, -1e30f};

    // one 32-col tile pair (n-frags N0, N0+1); m-frags sequenced; ALL
    // reduction maxes as guaranteed v_max3_f32
#define AHD_TILE(N0, YA, YB)                                                   \
    {                                                                          \
        const short8 b00 = *(const short8*)(ldsB + ob00 + (N0) * 2048);        \
        const short8 b01 = *(const short8*)(ldsB + ob01 + (N0) * 2048);        \
        const short8 b10 = *(const short8*)(ldsB + ob10 + (N0) * 2048);        \
        const short8 b11 = *(const short8*)(ldsB + ob11 + (N0) * 2048);        \
        const f32x2 ya2 = {(YA), (YA)}, yb2 = {(YB), (YB)};                    \
        float cm0 = -1e30f, cm1 = -1e30f;                                      \
        _Pragma("unroll")                                                      \
        for (int m = 0; m < 4; ++m) {                                          \
            const f32x2 p0 = xqlo[m] + ya2, p1 = xqhi[m] + ya2;                \
            const f32x2 q0 = xqlo[m] + yb2, q1 = xqhi[m] + yb2;                \
            f32x4 c0 = {p0.x, p0.y, p1.x, p1.y};                               \
            f32x4 c1 = {q0.x, q0.y, q1.x, q1.y};                               \
            c0 = __builtin_amdgcn_mfma_f32_16x16x32_bf16(afr[0][m], b00, c0, 0, 0, 0); \
            c1 = __builtin_amdgcn_mfma_f32_16x16x32_bf16(afr[0][m], b10, c1, 0, 0, 0); \
            c0 = __builtin_amdgcn_mfma_f32_16x16x32_bf16(afr[1][m], b01, c0, 0, 0, 0); \
            c1 = __builtin_amdgcn_mfma_f32_16x16x32_bf16(afr[1][m], b11, c1, 0, 0, 0); \
            rowm[m][0] = max3f(c0[0], c1[0], rowm[m][0]);                      \
            rowm[m][1] = max3f(c0[1], c1[1], rowm[m][1]);                      \
            rowm[m][2] = max3f(c0[2], c1[2], rowm[m][2]);                      \
            rowm[m][3] = max3f(c0[3], c1[3], rowm[m][3]);                      \
            cm0 = max3f(c0[3], max3f(c0[0], c0[1], c0[2]), cm0);               \
            cm1 = max3f(c1[3], max3f(c1[0], c1[1], c1[2]), cm1);               \
        }                                                                      \
        cm0 = fmaxf(cm0, __shfl_xor(cm0, 16));                                 \
        cm0 = fmaxf(cm0, __shfl_xor(cm0, 32));                                 \
        cm1 = fmaxf(cm1, __shfl_xor(cm1, 16));                                 \
        cm1 = fmaxf(cm1, __shfl_xor(cm1, 32));                                 \
        if (lh == 0) {                                                         \
            colbuf[w][(N0) * 16 + lr]      = cm0;                              \
            colbuf[w][(N0) * 16 + 16 + lr] = cm1;                              \
        }                                                                      \
    }

    AHD_TILE(0, yv0, yv1)
    AHD_TILE(2, yv2, yv3)
    AHD_TILE(4, yv4, yv5)
    AHD_TILE(6, yv6, yv7)
#undef AHD_TILE

    // ---- row partials: xor8 pre-reduce, conflict-free transpose into rowbuf
    #pragma unroll
    for (int m = 0; m < 4; ++m)
        #pragma unroll
        for (int j = 0; j < 4; ++j) {
            float v = rowm[m][j];
            v = fmaxf(v, __shfl_xor(v, 8));
            if (lr < 8) rowbuf[w][lh][lr][m * 4 + j] = v;
        }

    __syncthreads();   // rowbuf + colbuf complete

    // ---- row flush: each thread owns ONE of the block's 256 rows (max3 tree)
    {
        const int rw = tid >> 6, rr = tid & 63;
        const int rm = rr >> 4, rlh = (rr >> 2) & 3, rj = rr & 3;
        const float* p = &rowbuf[rw][rlh][0][rm * 4 + rj];
        const float t0 = max3f(p[0],      p[17],     p[2 * 17]);
        const float t1 = max3f(p[3 * 17], p[4 * 17], p[5 * 17]);
        const float t2 = fmaxf(p[6 * 17], p[7 * 17]);
        const float v  = max3f(t0, t1, t2);
        const float d2 = fmaxf(-2.f * v, 0.f);
        atomicMin(&rmin[brow + tid], __float_as_uint(d2));
    }

    // ---- col flush: merge the 4 wave slices, 1 col per thread (tid<128)
    if (tid < 128) {
        const float v = fmaxf(max3f(colbuf[0][tid], colbuf[1][tid], colbuf[2][tid]),
                              colbuf[3][tid]);
        const float d2 = fmaxf(-2.f * v, 0.f);
        atomicMin(&cmin[bcol + tid], __float_as_uint(d2));
    }
}

// ---------------------------------------------------------------------------
// finalize: out = mean(sqrt(rmin)) + mean(sqrt(cmin)); 1024 thr, uint4 loads.
// ---------------------------------------------------------------------------
__global__ __launch_bounds__(1024) void ahd_finalize(
    const unsigned int* __restrict__ rmin, const unsigned int* __restrict__ cmin,
    float* __restrict__ out, int N, int M)
{
    const int tid = threadIdx.x;
    const uint4* r4 = (const uint4*)rmin;
    const uint4* c4 = (const uint4*)cmin;
    float sa = 0.f, sb = 0.f;
    for (int i = tid; i < (N >> 2); i += 1024) {
        const uint4 v = r4[i];
        sa += sqrtf(__uint_as_float(v.x)) + sqrtf(__uint_as_float(v.y))
            + sqrtf(__uint_as_float(v.z)) + sqrtf(__uint_as_float(v.w));
    }
    for (int i = tid; i < (M >> 2); i += 1024) {
        const uint4 v = c4[i];
        sb += sqrtf(__uint_as_float(v.x)) + sqrtf(__uint_as_float(v.y))
            + sqrtf(__uint_as_float(v.z)) + sqrtf(__uint_as_float(v.w));
    }
    float v = sa / (float)N + sb / (float)M;
    #pragma unroll
    for (int s = 1; s < 64; s <<= 1) v += __shfl_xor(v, s);
    __shared__ float red[16];
    if ((tid & 63) == 0) red[tid >> 6] = v;
    __syncthreads();
    if (tid == 0) {
        float t = 0.f;
        #pragma unroll
        for (int i = 0; i < 16; ++i) t += red[i];
        out[0] = t;
    }
}

extern "C" void kernel_launch(void* const* d_in, const int* in_sizes, int n_in,
                              void* d_out, int out_size, void* d_ws, size_t ws_size,
                              hipStream_t stream) {
    const float* s1 = (const float*)d_in[0];
    const float* s2 = (const float*)d_in[1];
    const int N = in_sizes[0] / 64;
    const int M = in_sizes[1] / 64;

    char* ws = (char*)d_ws;
    __hip_bfloat16* abf = (__hip_bfloat16*)ws;
    __hip_bfloat16* bbf = (__hip_bfloat16*)(ws + (size_t)N * 128);
    float* xh = (float*)(ws + (size_t)(N + M) * 128);
    float* yh = xh + N;
    unsigned int* rmin = (unsigned int*)(yh + M);
    unsigned int* cmin = rmin + N;

    const int prows = ((N + M) * 16 + 255) / 256;
    ahd_prep<<<prows, 256, 0, stream>>>(s1, s2, abf, bbf, xh, yh,
                                        rmin, cmin, N, M);
    dim3 grid(N / 256, M / 128);    // 8192 blocks; x fastest; NO XCD swizzle
    ahd_gemm<<<grid, 256, 0, stream>>>(abf, bbf, xh, yh, rmin, cmin);
    ahd_finalize<<<1, 1024, 0, stream>>>(rmin, cmin, (float*)d_out, N, M);
}

// Round 17
// 67.121 us; speedup vs baseline: 1.4973x; 1.2029x over previous
//
#include <hip/hip_runtime.h>
#include <hip/hip_bf16.h>

typedef __attribute__((ext_vector_type(8))) short short8;  // 8 bf16 (4 VGPRs)
typedef __attribute__((ext_vector_type(4))) short short4v;
typedef __attribute__((ext_vector_type(4))) float f32x4;
typedef __attribute__((ext_vector_type(2))) float f32x2;

#define INF_BITS 0x7F800000u

// guaranteed single-instruction maxes (R16: +19us from bypassing fmaxf
// canonicalization glue; clang fusion is unreliable)
__device__ __forceinline__ float max3f(float a, float b, float c) {
    float d;
    asm("v_max3_f32 %0, %1, %2, %3" : "=v"(d) : "v"(a), "v"(b), "v"(c));
    return d;
}
__device__ __forceinline__ float vmaxf(float a, float b) {
    float d;
    asm("v_max_f32 %0, %1, %2" : "=v"(d) : "v"(a), "v"(b));
    return d;
}

// ---------------------------------------------------------------------------
// prep: fp32 -> bf16, h-norms (-0.5*||.||^2, fp32 exact), init min arrays.
// ---------------------------------------------------------------------------
__global__ __launch_bounds__(256) void ahd_prep(
    const float* __restrict__ s1, const float* __restrict__ s2,
    __hip_bfloat16* __restrict__ abf, __hip_bfloat16* __restrict__ bbf,
    float* __restrict__ xh, float* __restrict__ yh,
    unsigned int* __restrict__ rmin, unsigned int* __restrict__ cmin,
    int N, int M)
{
    const int t   = blockIdx.x * 256 + threadIdx.x;
    const int row = t >> 4;
    const int sub = t & 15;

    if (t < N)          rmin[t]     = INF_BITS;
    else if (t < N + M) cmin[t - N] = INF_BITS;

    const float* src; __hip_bfloat16* dst; float* nrm; int r;
    if (row < N)            { src = s1; dst = abf; nrm = xh; r = row; }
    else if (row < N + M)   { src = s2; dst = bbf; nrm = yh; r = row - N; }
    else return;

    const float4 v = *(const float4*)&src[(size_t)r * 64 + sub * 4];
    __hip_bfloat16 h0 = __float2bfloat16(v.x), h1 = __float2bfloat16(v.y);
    __hip_bfloat16 h2 = __float2bfloat16(v.z), h3 = __float2bfloat16(v.w);
    short4v sv = { *(short*)&h0, *(short*)&h1, *(short*)&h2, *(short*)&h3 };
    *(short4v*)&dst[(size_t)r * 64 + sub * 4] = sv;

    float ss = v.x * v.x + v.y * v.y + v.z * v.z + v.w * v.w;
    ss += __shfl_xor(ss, 1);
    ss += __shfl_xor(ss, 2);
    ss += __shfl_xor(ss, 4);
    ss += __shfl_xor(ss, 8);
    if (sub == 0) nrm[r] = -0.5f * ss;     // fold: MFMA C-init = xh + yh
}

// ---------------------------------------------------------------------------
// fused distance-GEMM + row/col min. R16 base (75.7us) + per-block fixed-cost
// halving: block 256x256 (8 tile-pairs/wave, was 4) -- staging drain, A/x/y
// prologue, barriers, flushes all amortize 2x (R16 accounting: fixed costs
// ~45% of wave time). All remaining reduction fmaxf -> forced v_max_f32.
// Structure otherwise identical: 4 waves x (64 rows x 256 cols), B block-
// deduped via global_load_lds + involution, C-init fold (min d^2 == max acc),
// forced v_max3 trees, LDS-transpose row flush, 2 barriers, no XCD swizzle.
// ---------------------------------------------------------------------------
__global__ __launch_bounds__(256) void ahd_gemm(
    const __hip_bfloat16* __restrict__ abf, const __hip_bfloat16* __restrict__ bbf,
    const float* __restrict__ xh, const float* __restrict__ yh,
    unsigned int* __restrict__ rmin, unsigned int* __restrict__ cmin)
{
    __shared__ __attribute__((aligned(128))) char ldsB[32768];
    __shared__ float rowbuf[4][4][8][17];   // [w][lh][lr<8][j16 +pad] = 8704 B
    __shared__ float colbuf[4][256];

    const int tid  = threadIdx.x;
    const int lane = tid & 63;
    const int w    = tid >> 6;
    const int lr   = lane & 15, lh = lane >> 4;   // lh in 0..3

    const int brow = blockIdx.x * 256;
    const int bcol = blockIdx.y * 256;

    // ---- stage B (32 KB): linear LDS dest + inverse-swizzled source
    const char* bT = (const char*)bbf + (size_t)bcol * 128;
    #pragma unroll
    for (int it = 0; it < 8; ++it) {
        const int dst = w * 1024 + it * 4096;
        const int o   = dst + lane * 16;
        const int so  = o ^ ((o >> 3) & 0x70);
        __builtin_amdgcn_global_load_lds(
            (const __attribute__((address_space(1))) void*)(bT + so),
            (__attribute__((address_space(3))) void*)(ldsB + dst), 16, 0, 0);
    }

    // ---- A fragments straight from global (wave-exclusive 64 rows, L2-hot)
    const char* aB = (const char*)abf + (size_t)(brow + w * 64 + lr) * 128 + lh * 16;
    short8 afr[2][4];   // [ks][m]
    #pragma unroll
    for (int m = 0; m < 4; ++m) {
        afr[0][m] = *(const short8*)(aB + m * 2048);
        afr[1][m] = *(const short8*)(aB + m * 2048 + 64);
    }

    // ---- norms while staging is in flight
    f32x2 xqlo[4], xqhi[4];
    #pragma unroll
    for (int m = 0; m < 4; ++m) {
        const f32x4 xv = *(const f32x4*)&xh[brow + w * 64 + m * 16 + lh * 4];
        xqlo[m] = (f32x2){xv[0], xv[1]};
        xqhi[m] = (f32x2){xv[2], xv[3]};
    }
    const float yv0 = yh[bcol + lr];
    const float yv1 = yh[bcol + 16 + lr];
    const float yv2 = yh[bcol + 32 + lr];
    const float yv3 = yh[bcol + 48 + lr];
    const float yv4 = yh[bcol + 64 + lr];
    const float yv5 = yh[bcol + 80 + lr];
    const float yv6 = yh[bcol + 96 + lr];
    const float yv7 = yh[bcol + 112 + lr];
    const float yv8 = yh[bcol + 128 + lr];
    const float yv9 = yh[bcol + 144 + lr];
    const float yvA = yh[bcol + 160 + lr];
    const float yvB = yh[bcol + 176 + lr];
    const float yvC = yh[bcol + 192 + lr];
    const float yvD = yh[bcol + 208 + lr];
    const float yvE = yh[bcol + 224 + lr];
    const float yvF = yh[bcol + 240 + lr];

    __syncthreads();   // drains B staging

    // ---- hoisted swizzled B-frag base offsets (+4096 per tile-pair is exact
    //      in swizzled space: XOR reads bits 9:7, writes 6:4)
    int ob00 = lr * 128 + lh * 16;              ob00 ^= (ob00 >> 3) & 0x70;
    int ob01 = lr * 128 + 64 + lh * 16;         ob01 ^= (ob01 >> 3) & 0x70;
    int ob10 = (16 + lr) * 128 + lh * 16;       ob10 ^= (ob10 >> 3) & 0x70;
    int ob11 = (16 + lr) * 128 + 64 + lh * 16;  ob11 ^= (ob11 >> 3) & 0x70;

    f32x4 rowm[4];
    #pragma unroll
    for (int m = 0; m < 4; ++m) rowm[m] = (f32x4){-1e30f, -1e30f, -1e30f, -1e30f};

    // one 32-col tile pair (n-frags N0, N0+1); m-frags sequenced; ALL
    // reduction maxes as guaranteed v_max3/v_max
#define AHD_TILE(N0, YA, YB)                                                   \
    {                                                                          \
        const short8 b00 = *(const short8*)(ldsB + ob00 + (N0) * 2048);        \
        const short8 b01 = *(const short8*)(ldsB + ob01 + (N0) * 2048);        \
        const short8 b10 = *(const short8*)(ldsB + ob10 + (N0) * 2048);        \
        const short8 b11 = *(const short8*)(ldsB + ob11 + (N0) * 2048);        \
        const f32x2 ya2 = {(YA), (YA)}, yb2 = {(YB), (YB)};                    \
        float cm0 = -1e30f, cm1 = -1e30f;                                      \
        _Pragma("unroll")                                                      \
        for (int m = 0; m < 4; ++m) {                                          \
            const f32x2 p0 = xqlo[m] + ya2, p1 = xqhi[m] + ya2;                \
            const f32x2 q0 = xqlo[m] + yb2, q1 = xqhi[m] + yb2;                \
            f32x4 c0 = {p0.x, p0.y, p1.x, p1.y};                               \
            f32x4 c1 = {q0.x, q0.y, q1.x, q1.y};                               \
            c0 = __builtin_amdgcn_mfma_f32_16x16x32_bf16(afr[0][m], b00, c0, 0, 0, 0); \
            c1 = __builtin_amdgcn_mfma_f32_16x16x32_bf16(afr[0][m], b10, c1, 0, 0, 0); \
            c0 = __builtin_amdgcn_mfma_f32_16x16x32_bf16(afr[1][m], b01, c0, 0, 0, 0); \
            c1 = __builtin_amdgcn_mfma_f32_16x16x32_bf16(afr[1][m], b11, c1, 0, 0, 0); \
            rowm[m][0] = max3f(c0[0], c1[0], rowm[m][0]);                      \
            rowm[m][1] = max3f(c0[1], c1[1], rowm[m][1]);                      \
            rowm[m][2] = max3f(c0[2], c1[2], rowm[m][2]);                      \
            rowm[m][3] = max3f(c0[3], c1[3], rowm[m][3]);                      \
            cm0 = max3f(c0[3], max3f(c0[0], c0[1], c0[2]), cm0);               \
            cm1 = max3f(c1[3], max3f(c1[0], c1[1], c1[2]), cm1);               \
        }                                                                      \
        cm0 = vmaxf(cm0, __shfl_xor(cm0, 16));                                 \
        cm0 = vmaxf(cm0, __shfl_xor(cm0, 32));                                 \
        cm1 = vmaxf(cm1, __shfl_xor(cm1, 16));                                 \
        cm1 = vmaxf(cm1, __shfl_xor(cm1, 32));                                 \
        if (lh == 0) {                                                         \
            colbuf[w][(N0) * 16 + lr]      = cm0;                              \
            colbuf[w][(N0) * 16 + 16 + lr] = cm1;                              \
        }                                                                      \
    }

    AHD_TILE(0,  yv0, yv1)
    AHD_TILE(2,  yv2, yv3)
    AHD_TILE(4,  yv4, yv5)
    AHD_TILE(6,  yv6, yv7)
    AHD_TILE(8,  yv8, yv9)
    AHD_TILE(10, yvA, yvB)
    AHD_TILE(12, yvC, yvD)
    AHD_TILE(14, yvE, yvF)
#undef AHD_TILE

    // ---- row partials: xor8 pre-reduce, conflict-free transpose into rowbuf
    #pragma unroll
    for (int m = 0; m < 4; ++m)
        #pragma unroll
        for (int j = 0; j < 4; ++j) {
            float v = rowm[m][j];
            v = vmaxf(v, __shfl_xor(v, 8));
            if (lr < 8) rowbuf[w][lh][lr][m * 4 + j] = v;
        }

    __syncthreads();   // rowbuf + colbuf complete

    // ---- row flush: each thread owns ONE of the block's 256 rows (max3 tree)
    {
        const int rw = tid >> 6, rr = tid & 63;
        const int rm = rr >> 4, rlh = (rr >> 2) & 3, rj = rr & 3;
        const float* p = &rowbuf[rw][rlh][0][rm * 4 + rj];
        const float t0 = max3f(p[0],      p[17],     p[2 * 17]);
        const float t1 = max3f(p[3 * 17], p[4 * 17], p[5 * 17]);
        const float t2 = vmaxf(p[6 * 17], p[7 * 17]);
        const float v  = max3f(t0, t1, t2);
        const float d2 = fmaxf(-2.f * v, 0.f);
        atomicMin(&rmin[brow + tid], __float_as_uint(d2));
    }

    // ---- col flush: merge the 4 wave slices, 1 col per thread (all 256)
    {
        const float v = vmaxf(max3f(colbuf[0][tid], colbuf[1][tid], colbuf[2][tid]),
                              colbuf[3][tid]);
        const float d2 = fmaxf(-2.f * v, 0.f);
        atomicMin(&cmin[bcol + tid], __float_as_uint(d2));
    }
}

// ---------------------------------------------------------------------------
// finalize: out = mean(sqrt(rmin)) + mean(sqrt(cmin)); 1024 thr, uint4 loads.
// ---------------------------------------------------------------------------
__global__ __launch_bounds__(1024) void ahd_finalize(
    const unsigned int* __restrict__ rmin, const unsigned int* __restrict__ cmin,
    float* __restrict__ out, int N, int M)
{
    const int tid = threadIdx.x;
    const uint4* r4 = (const uint4*)rmin;
    const uint4* c4 = (const uint4*)cmin;
    float sa = 0.f, sb = 0.f;
    for (int i = tid; i < (N >> 2); i += 1024) {
        const uint4 v = r4[i];
        sa += sqrtf(__uint_as_float(v.x)) + sqrtf(__uint_as_float(v.y))
            + sqrtf(__uint_as_float(v.z)) + sqrtf(__uint_as_float(v.w));
    }
    for (int i = tid; i < (M >> 2); i += 1024) {
        const uint4 v = c4[i];
        sb += sqrtf(__uint_as_float(v.x)) + sqrtf(__uint_as_float(v.y))
            + sqrtf(__uint_as_float(v.z)) + sqrtf(__uint_as_float(v.w));
    }
    float v = sa / (float)N + sb / (float)M;
    #pragma unroll
    for (int s = 1; s < 64; s <<= 1) v += __shfl_xor(v, s);
    __shared__ float red[16];
    if ((tid & 63) == 0) red[tid >> 6] = v;
    __syncthreads();
    if (tid == 0) {
        float t = 0.f;
        #pragma unroll
        for (int i = 0; i < 16; ++i) t += red[i];
        out[0] = t;
    }
}

extern "C" void kernel_launch(void* const* d_in, const int* in_sizes, int n_in,
                              void* d_out, int out_size, void* d_ws, size_t ws_size,
                              hipStream_t stream) {
    const float* s1 = (const float*)d_in[0];
    const float* s2 = (const float*)d_in[1];
    const int N = in_sizes[0] / 64;
    const int M = in_sizes[1] / 64;

    char* ws = (char*)d_ws;
    __hip_bfloat16* abf = (__hip_bfloat16*)ws;
    __hip_bfloat16* bbf = (__hip_bfloat16*)(ws + (size_t)N * 128);
    float* xh = (float*)(ws + (size_t)(N + M) * 128);
    float* yh = xh + N;
    unsigned int* rmin = (unsigned int*)(yh + M);
    unsigned int* cmin = rmin + N;

    const int prows = ((N + M) * 16 + 255) / 256;
    ahd_prep<<<prows, 256, 0, stream>>>(s1, s2, abf, bbf, xh, yh,
                                        rmin, cmin, N, M);
    dim3 grid(N / 256, M / 256);    // 4096 blocks; x fastest; NO XCD swizzle
    ahd_gemm<<<grid, 256, 0, stream>>>(abf, bbf, xh, yh, rmin, cmin);
    ahd_finalize<<<1, 1024, 0, stream>>>(rmin, cmin, (float*)d_out, N, M);
}

// Round 18
// 66.611 us; speedup vs baseline: 1.5088x; 1.0077x over previous
//
#include <hip/hip_runtime.h>
#include <hip/hip_bf16.h>

typedef __attribute__((ext_vector_type(8))) short short8;  // 8 bf16 (4 VGPRs)
typedef __attribute__((ext_vector_type(4))) short short4v;
typedef __attribute__((ext_vector_type(4))) float f32x4;

#define INF_BITS 0x7F800000u

// guaranteed single-instruction maxes (R16: +19us from bypassing fmaxf
// canonicalization glue; clang fusion is unreliable)
__device__ __forceinline__ float max3f(float a, float b, float c) {
    float d;
    asm("v_max3_f32 %0, %1, %2, %3" : "=v"(d) : "v"(a), "v"(b), "v"(c));
    return d;
}
__device__ __forceinline__ float vmaxf(float a, float b) {
    float d;
    asm("v_max_f32 %0, %1, %2" : "=v"(d) : "v"(a), "v"(b));
    return d;
}

// ---------------------------------------------------------------------------
// prep: fp32 -> bf16, h-norms (-0.5*||.||^2, fp32 exact), init min arrays.
// ---------------------------------------------------------------------------
__global__ __launch_bounds__(256) void ahd_prep(
    const float* __restrict__ s1, const float* __restrict__ s2,
    __hip_bfloat16* __restrict__ abf, __hip_bfloat16* __restrict__ bbf,
    float* __restrict__ xh, float* __restrict__ yh,
    unsigned int* __restrict__ rmin, unsigned int* __restrict__ cmin,
    int N, int M)
{
    const int t   = blockIdx.x * 256 + threadIdx.x;
    const int row = t >> 4;
    const int sub = t & 15;

    if (t < N)          rmin[t]     = INF_BITS;
    else if (t < N + M) cmin[t - N] = INF_BITS;

    const float* src; __hip_bfloat16* dst; float* nrm; int r;
    if (row < N)            { src = s1; dst = abf; nrm = xh; r = row; }
    else if (row < N + M)   { src = s2; dst = bbf; nrm = yh; r = row - N; }
    else return;

    const float4 v = *(const float4*)&src[(size_t)r * 64 + sub * 4];
    __hip_bfloat16 h0 = __float2bfloat16(v.x), h1 = __float2bfloat16(v.y);
    __hip_bfloat16 h2 = __float2bfloat16(v.z), h3 = __float2bfloat16(v.w);
    short4v sv = { *(short*)&h0, *(short*)&h1, *(short*)&h2, *(short*)&h3 };
    *(short4v*)&dst[(size_t)r * 64 + sub * 4] = sv;

    float ss = v.x * v.x + v.y * v.y + v.z * v.z + v.w * v.w;
    ss += __shfl_xor(ss, 1);
    ss += __shfl_xor(ss, 2);
    ss += __shfl_xor(ss, 4);
    ss += __shfl_xor(ss, 8);
    if (sub == 0) nrm[r] = -0.5f * ss;     // fold: MFMA C-init = xh + yh
}

// ---------------------------------------------------------------------------
// fused distance-GEMM + row/col min. R17 base (59.9us gemm) with ONE change:
// C-init in NATURAL f32x4 form (c0 = xqv[m] + ya4) so the adds are emitted
// directly into the register quad the MFMA consumes -- R17 split xq into
// f32x2 pairs and rebuilt f32x4s, costing ~1 mov/element of pure glue
// (R15/R17 accounting: emitted VALU ~3x source need; R16 proved emission
// glue is removable and large). Everything else identical: block 256x256,
// 4 waves x (64 rows x 256 cols), B block-deduped via global_load_lds +
// involution, C-init fold (min d^2 == max acc), forced v_max3/v_max trees,
// LDS-transpose row flush, 2 barriers, no XCD swizzle.
// ---------------------------------------------------------------------------
__global__ __launch_bounds__(256) void ahd_gemm(
    const __hip_bfloat16* __restrict__ abf, const __hip_bfloat16* __restrict__ bbf,
    const float* __restrict__ xh, const float* __restrict__ yh,
    unsigned int* __restrict__ rmin, unsigned int* __restrict__ cmin)
{
    __shared__ __attribute__((aligned(128))) char ldsB[32768];
    __shared__ float rowbuf[4][4][8][17];   // [w][lh][lr<8][j16 +pad] = 8704 B
    __shared__ float colbuf[4][256];

    const int tid  = threadIdx.x;
    const int lane = tid & 63;
    const int w    = tid >> 6;
    const int lr   = lane & 15, lh = lane >> 4;   // lh in 0..3

    const int brow = blockIdx.x * 256;
    const int bcol = blockIdx.y * 256;

    // ---- stage B (32 KB): linear LDS dest + inverse-swizzled source
    const char* bT = (const char*)bbf + (size_t)bcol * 128;
    #pragma unroll
    for (int it = 0; it < 8; ++it) {
        const int dst = w * 1024 + it * 4096;
        const int o   = dst + lane * 16;
        const int so  = o ^ ((o >> 3) & 0x70);
        __builtin_amdgcn_global_load_lds(
            (const __attribute__((address_space(1))) void*)(bT + so),
            (__attribute__((address_space(3))) void*)(ldsB + dst), 16, 0, 0);
    }

    // ---- A fragments straight from global (wave-exclusive 64 rows, L2-hot)
    const char* aB = (const char*)abf + (size_t)(brow + w * 64 + lr) * 128 + lh * 16;
    short8 afr[2][4];   // [ks][m]
    #pragma unroll
    for (int m = 0; m < 4; ++m) {
        afr[0][m] = *(const short8*)(aB + m * 2048);
        afr[1][m] = *(const short8*)(aB + m * 2048 + 64);
    }

    // ---- norms while staging is in flight (xqv kept as natural f32x4)
    f32x4 xqv[4];
    #pragma unroll
    for (int m = 0; m < 4; ++m)
        xqv[m] = *(const f32x4*)&xh[brow + w * 64 + m * 16 + lh * 4];

    const float yv0 = yh[bcol + lr];
    const float yv1 = yh[bcol + 16 + lr];
    const float yv2 = yh[bcol + 32 + lr];
    const float yv3 = yh[bcol + 48 + lr];
    const float yv4 = yh[bcol + 64 + lr];
    const float yv5 = yh[bcol + 80 + lr];
    const float yv6 = yh[bcol + 96 + lr];
    const float yv7 = yh[bcol + 112 + lr];
    const float yv8 = yh[bcol + 128 + lr];
    const float yv9 = yh[bcol + 144 + lr];
    const float yvA = yh[bcol + 160 + lr];
    const float yvB = yh[bcol + 176 + lr];
    const float yvC = yh[bcol + 192 + lr];
    const float yvD = yh[bcol + 208 + lr];
    const float yvE = yh[bcol + 224 + lr];
    const float yvF = yh[bcol + 240 + lr];

    __syncthreads();   // drains B staging

    // ---- hoisted swizzled B-frag base offsets (+4096 per tile-pair is exact
    //      in swizzled space: XOR reads bits 9:7, writes 6:4)
    int ob00 = lr * 128 + lh * 16;              ob00 ^= (ob00 >> 3) & 0x70;
    int ob01 = lr * 128 + 64 + lh * 16;         ob01 ^= (ob01 >> 3) & 0x70;
    int ob10 = (16 + lr) * 128 + lh * 16;       ob10 ^= (ob10 >> 3) & 0x70;
    int ob11 = (16 + lr) * 128 + 64 + lh * 16;  ob11 ^= (ob11 >> 3) & 0x70;

    f32x4 rowm[4];
    #pragma unroll
    for (int m = 0; m < 4; ++m) rowm[m] = (f32x4){-1e30f, -1e30f, -1e30f, -1e30f};

    // one 32-col tile pair (n-frags N0, N0+1); m-frags sequenced; NATURAL
    // f32x4 c-init; all reduction maxes as guaranteed v_max3/v_max
#define AHD_TILE(N0, YA, YB)                                                   \
    {                                                                          \
        const short8 b00 = *(const short8*)(ldsB + ob00 + (N0) * 2048);        \
        const short8 b01 = *(const short8*)(ldsB + ob01 + (N0) * 2048);        \
        const short8 b10 = *(const short8*)(ldsB + ob10 + (N0) * 2048);        \
        const short8 b11 = *(const short8*)(ldsB + ob11 + (N0) * 2048);        \
        const f32x4 ya4 = {(YA), (YA), (YA), (YA)};                            \
        const f32x4 yb4 = {(YB), (YB), (YB), (YB)};                            \
        float cm0 = -1e30f, cm1 = -1e30f;                                      \
        _Pragma("unroll")                                                      \
        for (int m = 0; m < 4; ++m) {                                          \
            f32x4 c0 = xqv[m] + ya4;   /* direct adds into MFMA C quad */      \
            f32x4 c1 = xqv[m] + yb4;                                           \
            c0 = __builtin_amdgcn_mfma_f32_16x16x32_bf16(afr[0][m], b00, c0, 0, 0, 0); \
            c1 = __builtin_amdgcn_mfma_f32_16x16x32_bf16(afr[0][m], b10, c1, 0, 0, 0); \
            c0 = __builtin_amdgcn_mfma_f32_16x16x32_bf16(afr[1][m], b01, c0, 0, 0, 0); \
            c1 = __builtin_amdgcn_mfma_f32_16x16x32_bf16(afr[1][m], b11, c1, 0, 0, 0); \
            rowm[m][0] = max3f(c0[0], c1[0], rowm[m][0]);                      \
            rowm[m][1] = max3f(c0[1], c1[1], rowm[m][1]);                      \
            rowm[m][2] = max3f(c0[2], c1[2], rowm[m][2]);                      \
            rowm[m][3] = max3f(c0[3], c1[3], rowm[m][3]);                      \
            cm0 = max3f(c0[3], max3f(c0[0], c0[1], c0[2]), cm0);               \
            cm1 = max3f(c1[3], max3f(c1[0], c1[1], c1[2]), cm1);               \
        }                                                                      \
        cm0 = vmaxf(cm0, __shfl_xor(cm0, 16));                                 \
        cm0 = vmaxf(cm0, __shfl_xor(cm0, 32));                                 \
        cm1 = vmaxf(cm1, __shfl_xor(cm1, 16));                                 \
        cm1 = vmaxf(cm1, __shfl_xor(cm1, 32));                                 \
        if (lh == 0) {                                                         \
            colbuf[w][(N0) * 16 + lr]      = cm0;                              \
            colbuf[w][(N0) * 16 + 16 + lr] = cm1;                              \
        }                                                                      \
    }

    AHD_TILE(0,  yv0, yv1)
    AHD_TILE(2,  yv2, yv3)
    AHD_TILE(4,  yv4, yv5)
    AHD_TILE(6,  yv6, yv7)
    AHD_TILE(8,  yv8, yv9)
    AHD_TILE(10, yvA, yvB)
    AHD_TILE(12, yvC, yvD)
    AHD_TILE(14, yvE, yvF)
#undef AHD_TILE

    // ---- row partials: xor8 pre-reduce, conflict-free transpose into rowbuf
    #pragma unroll
    for (int m = 0; m < 4; ++m)
        #pragma unroll
        for (int j = 0; j < 4; ++j) {
            float v = rowm[m][j];
            v = vmaxf(v, __shfl_xor(v, 8));
            if (lr < 8) rowbuf[w][lh][lr][m * 4 + j] = v;
        }

    __syncthreads();   // rowbuf + colbuf complete

    // ---- row flush: each thread owns ONE of the block's 256 rows (max3 tree)
    {
        const int rw = tid >> 6, rr = tid & 63;
        const int rm = rr >> 4, rlh = (rr >> 2) & 3, rj = rr & 3;
        const float* p = &rowbuf[rw][rlh][0][rm * 4 + rj];
        const float t0 = max3f(p[0],      p[17],     p[2 * 17]);
        const float t1 = max3f(p[3 * 17], p[4 * 17], p[5 * 17]);
        const float t2 = vmaxf(p[6 * 17], p[7 * 17]);
        const float v  = max3f(t0, t1, t2);
        const float d2 = fmaxf(-2.f * v, 0.f);
        atomicMin(&rmin[brow + tid], __float_as_uint(d2));
    }

    // ---- col flush: merge the 4 wave slices, 1 col per thread (all 256)
    {
        const float v = vmaxf(max3f(colbuf[0][tid], colbuf[1][tid], colbuf[2][tid]),
                              colbuf[3][tid]);
        const float d2 = fmaxf(-2.f * v, 0.f);
        atomicMin(&cmin[bcol + tid], __float_as_uint(d2));
    }
}

// ---------------------------------------------------------------------------
// finalize: out = mean(sqrt(rmin)) + mean(sqrt(cmin)); 1024 thr, uint4 loads.
// ---------------------------------------------------------------------------
__global__ __launch_bounds__(1024) void ahd_finalize(
    const unsigned int* __restrict__ rmin, const unsigned int* __restrict__ cmin,
    float* __restrict__ out, int N, int M)
{
    const int tid = threadIdx.x;
    const uint4* r4 = (const uint4*)rmin;
    const uint4* c4 = (const uint4*)cmin;
    float sa = 0.f, sb = 0.f;
    for (int i = tid; i < (N >> 2); i += 1024) {
        const uint4 v = r4[i];
        sa += sqrtf(__uint_as_float(v.x)) + sqrtf(__uint_as_float(v.y))
            + sqrtf(__uint_as_float(v.z)) + sqrtf(__uint_as_float(v.w));
    }
    for (int i = tid; i < (M >> 2); i += 1024) {
        const uint4 v = c4[i];
        sb += sqrtf(__uint_as_float(v.x)) + sqrtf(__uint_as_float(v.y))
            + sqrtf(__uint_as_float(v.z)) + sqrtf(__uint_as_float(v.w));
    }
    float v = sa / (float)N + sb / (float)M;
    #pragma unroll
    for (int s = 1; s < 64; s <<= 1) v += __shfl_xor(v, s);
    __shared__ float red[16];
    if ((tid & 63) == 0) red[tid >> 6] = v;
    __syncthreads();
    if (tid == 0) {
        float t = 0.f;
        #pragma unroll
        for (int i = 0; i < 16; ++i) t += red[i];
        out[0] = t;
    }
}

extern "C" void kernel_launch(void* const* d_in, const int* in_sizes, int n_in,
                              void* d_out, int out_size, void* d_ws, size_t ws_size,
                              hipStream_t stream) {
    const float* s1 = (const float*)d_in[0];
    const float* s2 = (const float*)d_in[1];
    const int N = in_sizes[0] / 64;
    const int M = in_sizes[1] / 64;

    char* ws = (char*)d_ws;
    __hip_bfloat16* abf = (__hip_bfloat16*)ws;
    __hip_bfloat16* bbf = (__hip_bfloat16*)(ws + (size_t)N * 128);
    float* xh = (float*)(ws + (size_t)(N + M) * 128);
    float* yh = xh + N;
    unsigned int* rmin = (unsigned int*)(yh + M);
    unsigned int* cmin = rmin + N;

    const int prows = ((N + M) * 16 + 255) / 256;
    ahd_prep<<<prows, 256, 0, stream>>>(s1, s2, abf, bbf, xh, yh,
                                        rmin, cmin, N, M);
    dim3 grid(N / 256, M / 256);    // 4096 blocks; x fastest; NO XCD swizzle
    ahd_gemm<<<grid, 256, 0, stream>>>(abf, bbf, xh, yh, rmin, cmin);
    ahd_finalize<<<1, 1024, 0, stream>>>(rmin, cmin, (float*)d_out, N, M);
}